// Round 11
// baseline (209.954 us; speedup 1.0000x reference)
//
#include <hip/hip_runtime.h>
#include <hip/hip_bf16.h>

#define S_LEN 4096
#define DIM   1024
#define NH    16
#define HD    64

typedef unsigned short u16;
typedef short  bf16x8 __attribute__((ext_vector_type(8)));
typedef float  f32x4  __attribute__((ext_vector_type(4)));

__device__ __forceinline__ u16 f2bf(float f){
  union { float f; unsigned u; } x; x.f = f;
  unsigned u = x.u;
  return (u16)((u + 0x7FFFu + ((u >> 16) & 1u)) >> 16);
}
__device__ __forceinline__ unsigned pk2(float a, float b){
  union { __hip_bfloat162 h; unsigned u; } x;
  x.h = __float22bfloat162_rn(float2{a, b});
  return x.u;
}
// async global->LDS, 16B per lane (dest must be wave-uniform base + lane*16)
__device__ __forceinline__ void ld2lds16(const u16* g, u16* l){
  __builtin_amdgcn_global_load_lds((const __attribute__((address_space(1))) void*)g,
                                   (__attribute__((address_space(3))) void*)l, 16, 0, 0);
}

// Q pre-scale: 1/sqrt(64) * log2(e)  (softmax in exp2 domain; v_exp_f32 = 2^x)
#define QSCALE 0.1803368801111204f

__global__ __launch_bounds__(256) void fill_sentinel(float* __restrict__ out, int n){
  int i = blockIdx.x * 256 + threadIdx.x;
  if (i < n) out[i] = 77.0f;
}

// ---------------- X fp32 -> bf16 (one-time) ----------------
__global__ __launch_bounds__(256) void conv_x(const float* __restrict__ X, u16* __restrict__ Xb){
  size_t i = ((size_t)blockIdx.x * 256 + threadIdx.x) * 8;
  float4 v0 = *(const float4*)(X + i);
  float4 v1 = *(const float4*)(X + i + 4);
  uint4 w;
  w.x = pk2(v0.x, v0.y); w.y = pk2(v0.z, v0.w);
  w.z = pk2(v1.x, v1.y); w.w = pk2(v1.z, v1.w);
  *(uint4*)(Xb + i) = w;
}

// ---------------- W fp32 [k][n] -> Wt bf16 [z][n][k] ----------------
__global__ __launch_bounds__(256) void transpose_w(
    const float* __restrict__ W0, const float* __restrict__ W1, const float* __restrict__ W2,
    u16* __restrict__ Wt)
{
  const float* W = blockIdx.z==0 ? W0 : blockIdx.z==1 ? W1 : W2;
  u16* T = Wt + (size_t)blockIdx.z * DIM * DIM;
  __shared__ __align__(16) u16 tile[64*72];
  int k0 = blockIdx.x*64, n0 = blockIdx.y*64;
  int t = threadIdx.x;
  #pragma unroll
  for (int i = 0; i < 4; ++i){
    int idx = t + i*256;
    int row = idx >> 4, col4 = (idx & 15) * 4;
    float4 v = *(const float4*)(W + (size_t)(k0+row)*DIM + n0 + col4);
    tile[(col4+0)*72 + row] = f2bf(v.x);
    tile[(col4+1)*72 + row] = f2bf(v.y);
    tile[(col4+2)*72 + row] = f2bf(v.z);
    tile[(col4+3)*72 + row] = f2bf(v.w);
  }
  __syncthreads();
  #pragma unroll
  for (int i = 0; i < 2; ++i){
    int idx = t + i*256;
    int n = idx >> 3, k16 = (idx & 7) * 8;
    *(int4*)(T + (size_t)(n0+n)*DIM + k0 + k16) = *(const int4*)(tile + n*72 + k16);
  }
}

// ---------------- shared epilogue: C-frags -> Q / Kf / Vf ----------------
// Vf key-slot mapping (R4): slot (c2, q_slot, jj) holds phys key
//   s = 16*(2*c2 + (jj>>2)) + 4*q_slot + (jj&3)
// chosen so that attn's PV B-operand is a pure register concat of the QK
// C-frags after exp (zero cross-lane traffic, no LDS P roundtrip).
__device__ __forceinline__ void qkv_epilogue(
    int z, int m0, int n0, int wm, int wn, int quad, int l15,
    const f32x4 acc[4][4], const float* bias,
    u16* __restrict__ qb, u16* __restrict__ kf_out, u16* __restrict__ vf_out)
{
  #pragma unroll
  for (int nt=0; nt<4; ++nt){
    int n = n0 + wn + nt*16 + l15;
    float bv = bias[n];
    int h = n >> 6, d = n & 63;
    #pragma unroll
    for (int mt=0; mt<4; ++mt){
      int mb = m0 + wm + mt*16 + quad*4;   // C/D: row=quad*4+reg, col=l15
      f32x4 c = acc[mt][nt];
      if (z == 0){
        #pragma unroll
        for (int r=0; r<4; ++r)
          qb[(size_t)(mb + r)*DIM + n] = f2bf((c[r] + bv) * QSCALE);
      } else if (z == 1){
        int half = d >> 5, quadk = (d >> 3) & 3, j = d & 7;
        #pragma unroll
        for (int r=0; r<4; ++r){
          int s = mb + r;
          size_t idx = ((((size_t)h*256 + (s >> 4))*2 + half)*64 + quadk*16 + (s & 15))*8 + j;
          kf_out[idx] = f2bf(c[r] + bv);
        }
      } else {
        // keys mb..mb+3: kn,q_slot,c2 constant across r; jj = jj0 + r
        int kt64 = mb >> 6;
        int kn   = (mb >> 4) & 3;
        int qsl  = (mb >> 2) & 3;
        int h2   = kn >> 1;
        int jj0  = (kn & 1) * 4;
        int dt = d >> 4, dl = d & 15;
        size_t base = (((((size_t)h*64 + kt64)*4 + dt)*2 + h2)*64 + qsl*16 + dl)*8 + jj0;
        ushort4 p;
        p.x = f2bf(c[0]+bv); p.y = f2bf(c[1]+bv);
        p.z = f2bf(c[2]+bv); p.w = f2bf(c[3]+bv);
        *(ushort4*)(vf_out + base) = p;
      }
    }
  }
}

// ---------------- fast QKV GEMM: bf16 in, global_load_lds staging ----------------
__global__ __launch_bounds__(256) void qkv_gemm_fast(
    const u16* __restrict__ Xbf, const u16* __restrict__ Wt,
    const float* __restrict__ b0, const float* __restrict__ b1, const float* __restrict__ b2,
    u16* __restrict__ qb, u16* __restrict__ kf_out, u16* __restrict__ vf_out)
{
  int z = blockIdx.z;
  const u16* Wz = Wt + (size_t)z * DIM * DIM;
  const float* bias = z==0 ? b0 : z==1 ? b1 : b2;

  __shared__ __align__(16) u16 As[128*32];
  __shared__ __align__(16) u16 Bs[128*32];

  int m0 = blockIdx.x * 128, n0 = blockIdx.y * 128;
  int t = threadIdx.x, wave = t >> 6, lane = t & 63, quad = lane >> 4, l15 = lane & 15;
  int wm = (wave >> 1) * 64, wn = (wave & 1) * 64;

  f32x4 acc[4][4];
  #pragma unroll
  for (int i=0;i<4;++i)
    #pragma unroll
    for (int j=0;j<4;++j) acc[i][j] = (f32x4){0.f,0.f,0.f,0.f};

  int srow = wave*32 + (lane >> 2);
  int skc  = (lane & 3) * 8;
  const u16* gA0 = Xbf + (size_t)(m0 + srow)*DIM + skc;
  const u16* gA1 = gA0 + (size_t)16*DIM;
  const u16* gB0 = Wz  + (size_t)(n0 + srow)*DIM + skc;
  const u16* gB1 = gB0 + (size_t)16*DIM;
  u16* lA0 = As + srow*32 + skc;
  u16* lA1 = lA0 + 16*32;
  u16* lB0 = Bs + srow*32 + skc;
  u16* lB1 = lB0 + 16*32;

  for (int kt = 0; kt < 32; ++kt){
    int ko = kt * 32;
    __syncthreads();
    ld2lds16(gA0 + ko, lA0);
    ld2lds16(gA1 + ko, lA1);
    ld2lds16(gB0 + ko, lB0);
    ld2lds16(gB1 + ko, lB1);
    __syncthreads();
    bf16x8 af[4], bfr[4];
    #pragma unroll
    for (int mt=0; mt<4; ++mt) af[mt]  = *(const bf16x8*)(As + (wm + mt*16 + l15)*32 + quad*8);
    #pragma unroll
    for (int nt=0; nt<4; ++nt) bfr[nt] = *(const bf16x8*)(Bs + (wn + nt*16 + l15)*32 + quad*8);
    #pragma unroll
    for (int mt=0; mt<4; ++mt)
      #pragma unroll
      for (int nt=0; nt<4; ++nt)
        acc[mt][nt] = __builtin_amdgcn_mfma_f32_16x16x32_bf16(af[mt], bfr[nt], acc[mt][nt], 0, 0, 0);
  }
  qkv_epilogue(z, m0, n0, wm, wn, quad, l15, acc, bias, qb, kf_out, vf_out);
}

// ---------------- legacy QKV GEMM (fp32 in; used when ws < 38 MB) ----------------
__global__ __launch_bounds__(256) void qkv_gemm_legacy(
    const float* __restrict__ X,
    const float* __restrict__ Wq, const float* __restrict__ Wk, const float* __restrict__ Wv,
    const float* __restrict__ b0, const float* __restrict__ b1, const float* __restrict__ b2,
    u16* __restrict__ qb, u16* __restrict__ kf_out, u16* __restrict__ vf_out)
{
  int z = blockIdx.z;
  const float* W    = z==0 ? Wq : z==1 ? Wk : Wv;
  const float* bias = z==0 ? b0 : z==1 ? b1 : b2;

  __shared__ __align__(16) u16 As[128*40];
  __shared__ __align__(16) u16 Bs[128*40];

  int m0 = blockIdx.x * 128, n0 = blockIdx.y * 128;
  int t = threadIdx.x, wave = t >> 6, lane = t & 63, quad = lane >> 4, l15 = lane & 15;
  int wm = (wave >> 1) * 64, wn = (wave & 1) * 64;

  f32x4 acc[4][4];
  #pragma unroll
  for (int i=0;i<4;++i)
    #pragma unroll
    for (int j=0;j<4;++j) acc[i][j] = (f32x4){0.f,0.f,0.f,0.f};

  int sr = t >> 2, sc = (t & 3) * 8;
  const float* gA0 = X + (size_t)(m0 + sr) * DIM + sc;
  const float* gA1 = X + (size_t)(m0 + 64 + sr) * DIM + sc;
  int br = t >> 3, bc = (t & 7) * 16;
  const float* gW = W + (size_t)br * DIM + n0 + bc;

  for (int kt = 0; kt < 32; ++kt){
    int ko = kt * 32;
    float4 a00 = *(const float4*)(gA0 + ko);
    float4 a01 = *(const float4*)(gA0 + ko + 4);
    float4 a10 = *(const float4*)(gA1 + ko);
    float4 a11 = *(const float4*)(gA1 + ko + 4);
    float4 w0  = *(const float4*)(gW + (size_t)ko*DIM);
    float4 w1  = *(const float4*)(gW + (size_t)ko*DIM + 4);
    float4 w2  = *(const float4*)(gW + (size_t)ko*DIM + 8);
    float4 w3  = *(const float4*)(gW + (size_t)ko*DIM + 12);
    int4 pa0, pa1;
    pa0.x = pk2(a00.x,a00.y); pa0.y = pk2(a00.z,a00.w);
    pa0.z = pk2(a01.x,a01.y); pa0.w = pk2(a01.z,a01.w);
    pa1.x = pk2(a10.x,a10.y); pa1.y = pk2(a10.z,a10.w);
    pa1.z = pk2(a11.x,a11.y); pa1.w = pk2(a11.z,a11.w);
    u16 wb[16];
    wb[0]=f2bf(w0.x); wb[1]=f2bf(w0.y); wb[2]=f2bf(w0.z); wb[3]=f2bf(w0.w);
    wb[4]=f2bf(w1.x); wb[5]=f2bf(w1.y); wb[6]=f2bf(w1.z); wb[7]=f2bf(w1.w);
    wb[8]=f2bf(w2.x); wb[9]=f2bf(w2.y); wb[10]=f2bf(w2.z); wb[11]=f2bf(w2.w);
    wb[12]=f2bf(w3.x); wb[13]=f2bf(w3.y); wb[14]=f2bf(w3.z); wb[15]=f2bf(w3.w);
    __syncthreads();
    *(int4*)(As + sr*40 + sc)      = pa0;
    *(int4*)(As + (64+sr)*40 + sc) = pa1;
    #pragma unroll
    for (int j=0;j<16;++j) Bs[(bc+j)*40 + br] = wb[j];
    __syncthreads();
    bf16x8 af[4], bfr[4];
    #pragma unroll
    for (int mt=0; mt<4; ++mt) af[mt]  = *(const bf16x8*)(As + (wm + mt*16 + l15)*40 + quad*8);
    #pragma unroll
    for (int nt=0; nt<4; ++nt) bfr[nt] = *(const bf16x8*)(Bs + (wn + nt*16 + l15)*40 + quad*8);
    #pragma unroll
    for (int mt=0; mt<4; ++mt)
      #pragma unroll
      for (int nt=0; nt<4; ++nt)
        acc[mt][nt] = __builtin_amdgcn_mfma_f32_16x16x32_bf16(af[mt], bfr[nt], acc[mt][nt], 0, 0, 0);
  }
  qkv_epilogue(z, m0, n0, wm, wn, quad, l15, acc, bias, qb, kf_out, vf_out);
}

// ---------------- flash attention: deferred-PV role split (wave de-phasing) ----------------
// R11: 8 schedule variants all plateau at 90-94us with MfmaUtil~31/VALUBusy~47 and
// period ~= matrix + VALU + overhead summed SERIALLY -> pipes have ZERO overlap.
// Cause: each SIMD hosts same-index waves of 2 co-resident blocks running identical
// phase sequences -> contention phase-locks them. Fix: role-split. dg =
// (wave&1)^((fid>>8)&1): natural waves run QK->exp->PV(t); deferred waves run
// PV(t-1) (pf/vfr CARRIED IN REGISTERS across the barrier - no LDS hazard) ->
// QK->exp(t). The fid>>8 parity flips roles between co-resident blocks (fid,
// fid+256) so each SIMD gets one QK-phase + one PV-phase wave -> MFMA||VALU
// overlap. s_setprio(1) around MFMA clusters (T5 pays only with role diversity).
// Per-wave op order identical to R8 -> bit-identical numerics.
__global__ __launch_bounds__(256, 2) void attn(
    const u16* __restrict__ Qb, const u16* __restrict__ Kf,
    const u16* __restrict__ Vf, float* __restrict__ out)
{
  int fid = blockIdx.x;                 // 0..511
  int xcd  = fid & 7;                   // XCD assignment (id % 8)
  int hpar = (fid >> 3) & 1;
  int qb   = fid >> 4;                  // 0..31
  int h    = xcd*2 + hpar;              // heads {2x, 2x+1} pinned to XCD x

  int t = threadIdx.x, wave = t >> 6, lane = t & 63, quad = lane >> 4, l15 = lane & 15;
  int q0 = qb * 128 + wave * 32;
  int dg = (wave ^ (fid >> 8)) & 1;     // 0 = natural, 1 = deferred-PV

  __shared__ __align__(16) u16 Ks0[4096], Ks1[4096], Vs0[4096], Vs1[4096];

  const u16* Kfh = Kf + (size_t)h * 262144;
  const u16* Vfh = Vf + (size_t)h * 262144;

  bf16x8 qf[2][2];
  #pragma unroll
  for (int qs=0; qs<2; ++qs){
    const u16* Qp = Qb + (size_t)(q0 + qs*16 + l15)*DIM + h*HD;
    qf[qs][0] = *(const bf16x8*)(Qp + quad*8);
    qf[qs][1] = *(const bf16x8*)(Qp + 32 + quad*8);
  }

  f32x4 O[2][4];
  #pragma unroll
  for (int qs=0; qs<2; ++qs)
    #pragma unroll
    for (int dt=0; dt<4; ++dt) O[qs][dt] = (f32x4){0.f,0.f,0.f,0.f};
  float lsum[2] = {0.f, 0.f};

  typedef union { uint4 u; bf16x8 v; } pfu;

#define STAGE(KS, VS, T)                                                         \
  do {                                                                           \
    const u16* kg_ = Kfh + (size_t)(T)*4096 + t*8;                               \
    ld2lds16(kg_,        KS + t*8);                                              \
    ld2lds16(kg_ + 2048, KS + t*8 + 2048);                                       \
    const u16* vg_ = Vfh + (size_t)(T)*4096 + t*8;                               \
    ld2lds16(vg_,        VS + t*8);                                              \
    ld2lds16(vg_ + 2048, VS + t*8 + 2048);                                       \
  } while(0)

// QK MFMAs (setprio-wrapped) + exp2 + pack -> PF
#define QK_EXP(KS, PF)                                                           \
  do {                                                                           \
    bf16x8 kfr[4][2];                                                            \
    _Pragma("unroll")                                                            \
    for (int kn=0; kn<4; ++kn)                                                   \
      _Pragma("unroll")                                                          \
      for (int hf=0; hf<2; ++hf)                                                 \
        kfr[kn][hf] = *(const bf16x8*)((KS) + (kn*2+hf)*512 + lane*8);           \
    f32x4 st[2][4];                                                              \
    __builtin_amdgcn_s_setprio(1);                                               \
    _Pragma("unroll")                                                            \
    for (int qs=0; qs<2; ++qs)                                                   \
      _Pragma("unroll")                                                          \
      for (int kn=0; kn<4; ++kn){                                                \
        f32x4 zz = (f32x4){0.f,0.f,0.f,0.f};                                     \
        zz = __builtin_amdgcn_mfma_f32_16x16x32_bf16(kfr[kn][0], qf[qs][0], zz, 0,0,0); \
        zz = __builtin_amdgcn_mfma_f32_16x16x32_bf16(kfr[kn][1], qf[qs][1], zz, 0,0,0); \
        st[qs][kn] = zz;                                                         \
      }                                                                          \
    __builtin_amdgcn_s_setprio(0);                                               \
    _Pragma("unroll")                                                            \
    for (int qs=0; qs<2; ++qs){                                                  \
      float ls = 0.f;                                                            \
      _Pragma("unroll")                                                          \
      for (int kn=0; kn<4; ++kn)                                                 \
        _Pragma("unroll")                                                        \
        for (int r=0; r<4; ++r){                                                 \
          float p = __builtin_amdgcn_exp2f(st[qs][kn][r]);                       \
          st[qs][kn][r] = p; ls += p;                                            \
        }                                                                        \
      lsum[qs] += ls;                                                            \
      PF[qs][0].u.x = pk2(st[qs][0][0], st[qs][0][1]);                           \
      PF[qs][0].u.y = pk2(st[qs][0][2], st[qs][0][3]);                           \
      PF[qs][0].u.z = pk2(st[qs][1][0], st[qs][1][1]);                           \
      PF[qs][0].u.w = pk2(st[qs][1][2], st[qs][1][3]);                           \
      PF[qs][1].u.x = pk2(st[qs][2][0], st[qs][2][1]);                           \
      PF[qs][1].u.y = pk2(st[qs][2][2], st[qs][2][3]);                           \
      PF[qs][1].u.z = pk2(st[qs][3][0], st[qs][3][1]);                           \
      PF[qs][1].u.w = pk2(st[qs][3][2], st[qs][3][3]);                           \
    }                                                                            \
  } while(0)

#define LOADV(VFR, VS)                                                           \
  do {                                                                           \
    _Pragma("unroll")                                                            \
    for (int dt=0; dt<4; ++dt)                                                   \
      _Pragma("unroll")                                                          \
      for (int c2=0; c2<2; ++c2)                                                 \
        VFR[dt][c2] = *(const bf16x8*)((VS) + (dt*2+c2)*512 + lane*8);           \
  } while(0)

#define PV(PF, VFR)                                                              \
  do {                                                                           \
    __builtin_amdgcn_s_setprio(1);                                               \
    _Pragma("unroll")                                                            \
    for (int qs=0; qs<2; ++qs)                                                   \
      _Pragma("unroll")                                                          \
      for (int dt=0; dt<4; ++dt){                                                \
        f32x4 o = O[qs][dt];                                                     \
        o = __builtin_amdgcn_mfma_f32_16x16x32_bf16(VFR[dt][0], PF[qs][0].v, o, 0,0,0); \
        o = __builtin_amdgcn_mfma_f32_16x16x32_bf16(VFR[dt][1], PF[qs][1].v, o, 0,0,0); \
        O[qs][dt] = o;                                                           \
      }                                                                          \
    __builtin_amdgcn_s_setprio(0);                                               \
  } while(0)

// role-branched tile body; FIRST=1 only for tile 0 (deferred has no PV yet)
#define COMPUTE(KS, VS, FIRST)                                                   \
  do {                                                                           \
    if (!dg){                                                                    \
      pfu pfN[2][2]; bf16x8 vfrN[4][2];                                          \
      QK_EXP(KS, pfN);                                                           \
      LOADV(vfrN, VS);                                                           \
      PV(pfN, vfrN);                                                             \
    } else {                                                                     \
      if (!(FIRST)) PV(pfC, vfrC);                                               \
      QK_EXP(KS, pfC);                                                           \
      LOADV(vfrC, VS);                                                           \
    }                                                                            \
  } while(0)

  pfu pfC[2][2];            // deferred-wave carried P-frags (live across barrier)
  bf16x8 vfrC[4][2];        // deferred-wave carried V-frags

  STAGE(Ks0, Vs0, 0);
  __syncthreads();
  // tile 0 (buf0): stage 1 into buf1
  STAGE(Ks1, Vs1, 1);
  COMPUTE(Ks0, Vs0, 1);
  __syncthreads();

  for (int kt = 1; kt < 63; kt += 2){
    // tile kt (odd, buf1): stage kt+1 (even) into buf0
    STAGE(Ks0, Vs0, kt+1);
    COMPUTE(Ks1, Vs1, 0);
    __syncthreads();
    // tile kt+1 (even, buf0): stage kt+2 (odd) into buf1
    STAGE(Ks1, Vs1, kt+2);
    COMPUTE(Ks0, Vs0, 0);
    __syncthreads();
  }
  // tile 63 (odd, buf1); no further staging
  COMPUTE(Ks1, Vs1, 0);
  if (dg) PV(pfC, vfrC);    // deferred wave finishes PV(63)

#undef STAGE
#undef QK_EXP
#undef LOADV
#undef PV
#undef COMPUTE

  #pragma unroll
  for (int qs=0; qs<2; ++qs){
    float l = lsum[qs];
    l += __shfl_xor(l, 16, 64);
    l += __shfl_xor(l, 32, 64);
    float inv = 1.0f / l;
    int query = q0 + qs*16 + l15;
    #pragma unroll
    for (int dt=0; dt<4; ++dt){
      float4 v;
      v.x = O[qs][dt][0]*inv; v.y = O[qs][dt][1]*inv;
      v.z = O[qs][dt][2]*inv; v.w = O[qs][dt][3]*inv;
      *(float4*)(out + (size_t)query*DIM + h*HD + dt*16 + quad*4) = v;
    }
  }
}

extern "C" void kernel_launch(void* const* d_in, const int* in_sizes, int n_in,
                              void* d_out, int out_size, void* d_ws, size_t ws_size,
                              hipStream_t stream)
{
  const float* X  = (const float*)d_in[0];
  const float* Wq = (const float*)d_in[1];
  const float* bq = (const float*)d_in[2];
  const float* Wk = (const float*)d_in[3];
  const float* bk = (const float*)d_in[4];
  const float* Wv = (const float*)d_in[5];
  const float* bv = (const float*)d_in[6];
  float* out = (float*)d_out;
  u16*   ws  = (u16*)d_ws;

  const size_t SD = (size_t)S_LEN * DIM;
  const size_t need_fast = (4*SD + 3*(size_t)DIM*DIM) * sizeof(u16);  // ~38 MB
  const size_t need_min  = (size_t)24 * 1024 * 1024;

  if (ws_size >= need_fast){
    u16* xbf = ws;
    u16* wt  = xbf + SD;
    u16* qb  = wt + 3*(size_t)DIM*DIM;
    u16* kf  = qb + SD;
    u16* vf  = kf + SD;
    conv_x       <<<dim3((int)(SD/8/256)), 256, 0, stream>>>(X, xbf);
    transpose_w  <<<dim3(16,16,3), 256, 0, stream>>>(Wq, Wk, Wv, wt);
    qkv_gemm_fast<<<dim3(32, 8, 3), 256, 0, stream>>>(xbf, wt, bq, bk, bv, qb, kf, vf);
    attn         <<<dim3(512), 256, 0, stream>>>(qb, kf, vf, out);
  } else if (ws_size >= need_min){
    u16* qb = ws;
    u16* kf = qb + SD;
    u16* vf = kf + SD;
    qkv_gemm_legacy<<<dim3(32, 8, 3), 256, 0, stream>>>(X, Wq, Wk, Wv, bq, bk, bv, qb, kf, vf);
    attn           <<<dim3(512), 256, 0, stream>>>(qb, kf, vf, out);
  } else {
    fill_sentinel<<<(out_size + 255)/256, 256, 0, stream>>>(out, out_size);
  }
}

// Round 12
// 208.859 us; speedup vs baseline: 1.0052x; 1.0052x over previous
//
#include <hip/hip_runtime.h>
#include <hip/hip_bf16.h>

#define S_LEN 4096
#define DIM   1024
#define NH    16
#define HD    64

typedef unsigned short u16;
typedef short  bf16x8 __attribute__((ext_vector_type(8)));
typedef float  f32x4  __attribute__((ext_vector_type(4)));

__device__ __forceinline__ u16 f2bf(float f){
  union { float f; unsigned u; } x; x.f = f;
  unsigned u = x.u;
  return (u16)((u + 0x7FFFu + ((u >> 16) & 1u)) >> 16);
}
__device__ __forceinline__ unsigned pk2(float a, float b){
  union { __hip_bfloat162 h; unsigned u; } x;
  x.h = __float22bfloat162_rn(float2{a, b});
  return x.u;
}
// async global->LDS, 16B per lane (dest must be wave-uniform base + lane*16)
__device__ __forceinline__ void ld2lds16(const u16* g, u16* l){
  __builtin_amdgcn_global_load_lds((const __attribute__((address_space(1))) void*)g,
                                   (__attribute__((address_space(3))) void*)l, 16, 0, 0);
}

// Q pre-scale: 1/sqrt(64) * log2(e)  (softmax in exp2 domain; v_exp_f32 = 2^x)
#define QSCALE 0.1803368801111204f

__global__ __launch_bounds__(256) void fill_sentinel(float* __restrict__ out, int n){
  int i = blockIdx.x * 256 + threadIdx.x;
  if (i < n) out[i] = 77.0f;
}

// ---------------- X fp32 -> bf16 (one-time) ----------------
__global__ __launch_bounds__(256) void conv_x(const float* __restrict__ X, u16* __restrict__ Xb){
  size_t i = ((size_t)blockIdx.x * 256 + threadIdx.x) * 8;
  float4 v0 = *(const float4*)(X + i);
  float4 v1 = *(const float4*)(X + i + 4);
  uint4 w;
  w.x = pk2(v0.x, v0.y); w.y = pk2(v0.z, v0.w);
  w.z = pk2(v1.x, v1.y); w.w = pk2(v1.z, v1.w);
  *(uint4*)(Xb + i) = w;
}

// ---------------- W fp32 [k][n] -> Wt bf16 [z][n][k] ----------------
__global__ __launch_bounds__(256) void transpose_w(
    const float* __restrict__ W0, const float* __restrict__ W1, const float* __restrict__ W2,
    u16* __restrict__ Wt)
{
  const float* W = blockIdx.z==0 ? W0 : blockIdx.z==1 ? W1 : W2;
  u16* T = Wt + (size_t)blockIdx.z * DIM * DIM;
  __shared__ __align__(16) u16 tile[64*72];
  int k0 = blockIdx.x*64, n0 = blockIdx.y*64;
  int t = threadIdx.x;
  #pragma unroll
  for (int i = 0; i < 4; ++i){
    int idx = t + i*256;
    int row = idx >> 4, col4 = (idx & 15) * 4;
    float4 v = *(const float4*)(W + (size_t)(k0+row)*DIM + n0 + col4);
    tile[(col4+0)*72 + row] = f2bf(v.x);
    tile[(col4+1)*72 + row] = f2bf(v.y);
    tile[(col4+2)*72 + row] = f2bf(v.z);
    tile[(col4+3)*72 + row] = f2bf(v.w);
  }
  __syncthreads();
  #pragma unroll
  for (int i = 0; i < 2; ++i){
    int idx = t + i*256;
    int n = idx >> 3, k16 = (idx & 7) * 8;
    *(int4*)(T + (size_t)(n0+n)*DIM + k0 + k16) = *(const int4*)(tile + n*72 + k16);
  }
}

// ---------------- shared epilogue: C-frags -> Q / Kf / Vf ----------------
// Vf key-slot mapping (R4): slot (c2, q_slot, jj) holds phys key
//   s = 16*(2*c2 + (jj>>2)) + 4*q_slot + (jj&3)
// chosen so that attn's PV B-operand is a pure register concat of the QK
// C-frags after exp (zero cross-lane traffic, no LDS P roundtrip).
__device__ __forceinline__ void qkv_epilogue(
    int z, int m0, int n0, int wm, int wn, int quad, int l15,
    const f32x4 acc[4][4], const float* bias,
    u16* __restrict__ qb, u16* __restrict__ kf_out, u16* __restrict__ vf_out)
{
  #pragma unroll
  for (int nt=0; nt<4; ++nt){
    int n = n0 + wn + nt*16 + l15;
    float bv = bias[n];
    int h = n >> 6, d = n & 63;
    #pragma unroll
    for (int mt=0; mt<4; ++mt){
      int mb = m0 + wm + mt*16 + quad*4;   // C/D: row=quad*4+reg, col=l15
      f32x4 c = acc[mt][nt];
      if (z == 0){
        #pragma unroll
        for (int r=0; r<4; ++r)
          qb[(size_t)(mb + r)*DIM + n] = f2bf((c[r] + bv) * QSCALE);
      } else if (z == 1){
        int half = d >> 5, quadk = (d >> 3) & 3, j = d & 7;
        #pragma unroll
        for (int r=0; r<4; ++r){
          int s = mb + r;
          size_t idx = ((((size_t)h*256 + (s >> 4))*2 + half)*64 + quadk*16 + (s & 15))*8 + j;
          kf_out[idx] = f2bf(c[r] + bv);
        }
      } else {
        // keys mb..mb+3: kn,q_slot,c2 constant across r; jj = jj0 + r
        int kt64 = mb >> 6;
        int kn   = (mb >> 4) & 3;
        int qsl  = (mb >> 2) & 3;
        int h2   = kn >> 1;
        int jj0  = (kn & 1) * 4;
        int dt = d >> 4, dl = d & 15;
        size_t base = (((((size_t)h*64 + kt64)*4 + dt)*2 + h2)*64 + qsl*16 + dl)*8 + jj0;
        ushort4 p;
        p.x = f2bf(c[0]+bv); p.y = f2bf(c[1]+bv);
        p.z = f2bf(c[2]+bv); p.w = f2bf(c[3]+bv);
        *(ushort4*)(vf_out + base) = p;
      }
    }
  }
}

// ---------------- fast QKV GEMM: bf16 in, global_load_lds + LDS XOR-swizzle ----------------
// R12 changes (GEMM only):
//  (a) LDS chunk swizzle per rule #21: gload_lds dest stays LINEAR; each lane's
//      GLOBAL source offset is pre-permuted (chunk c' loads global chunk
//      c'^((row>>1)&3)); frag reads apply the same XOR. Kills the 8-way bank
//      conflict of the 64B-row layout (row-bank period 2 -> with (row%2,(row>>1)&3)
//      period 8, 2 lanes/bank-group = free, m136). Zero extra instructions —
//      offsets are static per lane.
//  (b) XCD-locality grid: flat 768 blocks; each XCD gets 4 consecutive m-tiles of
//      one z -> per-XCD L2 working set 1MB X + 2MB W < 4MB (same fix class as the
//      attn head swizzle, FETCH-verified in R7).
__global__ __launch_bounds__(256) void qkv_gemm_fast(
    const u16* __restrict__ Xbf, const u16* __restrict__ Wt,
    const float* __restrict__ b0, const float* __restrict__ b1, const float* __restrict__ b2,
    u16* __restrict__ qb, u16* __restrict__ kf_out, u16* __restrict__ vf_out)
{
  int fid = blockIdx.x;                 // 0..767
  int z   = fid >> 8;                   // 0..2
  int r   = fid & 255;
  int m0  = (((r & 7) << 2) + ((r >> 3) & 3)) * 128;  // XCD r&7 owns m-tiles [xcd*4, xcd*4+4)
  int n0  = (r >> 5) * 128;                            // 0..7

  const u16* Wz = Wt + (size_t)z * DIM * DIM;
  const float* bias = z==0 ? b0 : z==1 ? b1 : b2;

  __shared__ __align__(16) u16 As[128*32];
  __shared__ __align__(16) u16 Bs[128*32];

  int t = threadIdx.x, wave = t >> 6, lane = t & 63, quad = lane >> 4, l15 = lane & 15;
  int wm = (wave >> 1) * 64, wn = (wave & 1) * 64;

  f32x4 acc[4][4];
  #pragma unroll
  for (int i=0;i<4;++i)
    #pragma unroll
    for (int j=0;j<4;++j) acc[i][j] = (f32x4){0.f,0.f,0.f,0.f};

  int srow = wave*32 + (lane >> 2);
  // global source chunk for this lane (inverse swizzle): c = (lane&3) ^ ((srow>>1)&3)
  int skc_g = (((lane & 3) ^ ((lane >> 3) & 3))) * 8;
  // linear LDS dest chunk (wave-uniform base + lane*16B)
  int skc_l = (lane & 3) * 8;
  const u16* gA0 = Xbf + (size_t)(m0 + srow)*DIM + skc_g;
  const u16* gA1 = gA0 + (size_t)16*DIM;
  const u16* gB0 = Wz  + (size_t)(n0 + srow)*DIM + skc_g;
  const u16* gB1 = gB0 + (size_t)16*DIM;
  u16* lA0 = As + srow*32 + skc_l;
  u16* lA1 = lA0 + 16*32;
  u16* lB0 = Bs + srow*32 + skc_l;
  u16* lB1 = lB0 + 16*32;

  // swizzled read offset: chunk q of row r lives at chunk q^((r>>1)&3); (r>>1)&3 == (l15>>1)&3
  int swz = (quad ^ ((l15 >> 1) & 3)) * 8;

  for (int kt = 0; kt < 32; ++kt){
    int ko = kt * 32;
    __syncthreads();
    ld2lds16(gA0 + ko, lA0);
    ld2lds16(gA1 + ko, lA1);
    ld2lds16(gB0 + ko, lB0);
    ld2lds16(gB1 + ko, lB1);
    __syncthreads();
    bf16x8 af[4], bfr[4];
    #pragma unroll
    for (int mt=0; mt<4; ++mt) af[mt]  = *(const bf16x8*)(As + (wm + mt*16 + l15)*32 + swz);
    #pragma unroll
    for (int nt=0; nt<4; ++nt) bfr[nt] = *(const bf16x8*)(Bs + (wn + nt*16 + l15)*32 + swz);
    #pragma unroll
    for (int mt=0; mt<4; ++mt)
      #pragma unroll
      for (int nt=0; nt<4; ++nt)
        acc[mt][nt] = __builtin_amdgcn_mfma_f32_16x16x32_bf16(af[mt], bfr[nt], acc[mt][nt], 0, 0, 0);
  }
  qkv_epilogue(z, m0, n0, wm, wn, quad, l15, acc, bias, qb, kf_out, vf_out);
}

// ---------------- legacy QKV GEMM (fp32 in; used when ws < 38 MB) ----------------
__global__ __launch_bounds__(256) void qkv_gemm_legacy(
    const float* __restrict__ X,
    const float* __restrict__ Wq, const float* __restrict__ Wk, const float* __restrict__ Wv,
    const float* __restrict__ b0, const float* __restrict__ b1, const float* __restrict__ b2,
    u16* __restrict__ qb, u16* __restrict__ kf_out, u16* __restrict__ vf_out)
{
  int z = blockIdx.z;
  const float* W    = z==0 ? Wq : z==1 ? Wk : Wv;
  const float* bias = z==0 ? b0 : z==1 ? b1 : b2;

  __shared__ __align__(16) u16 As[128*40];
  __shared__ __align__(16) u16 Bs[128*40];

  int m0 = blockIdx.x * 128, n0 = blockIdx.y * 128;
  int t = threadIdx.x, wave = t >> 6, lane = t & 63, quad = lane >> 4, l15 = lane & 15;
  int wm = (wave >> 1) * 64, wn = (wave & 1) * 64;

  f32x4 acc[4][4];
  #pragma unroll
  for (int i=0;i<4;++i)
    #pragma unroll
    for (int j=0;j<4;++j) acc[i][j] = (f32x4){0.f,0.f,0.f,0.f};

  int sr = t >> 2, sc = (t & 3) * 8;
  const float* gA0 = X + (size_t)(m0 + sr) * DIM + sc;
  const float* gA1 = X + (size_t)(m0 + 64 + sr) * DIM + sc;
  int br = t >> 3, bc = (t & 7) * 16;
  const float* gW = W + (size_t)br * DIM + n0 + bc;

  for (int kt = 0; kt < 32; ++kt){
    int ko = kt * 32;
    float4 a00 = *(const float4*)(gA0 + ko);
    float4 a01 = *(const float4*)(gA0 + ko + 4);
    float4 a10 = *(const float4*)(gA1 + ko);
    float4 a11 = *(const float4*)(gA1 + ko + 4);
    float4 w0  = *(const float4*)(gW + (size_t)ko*DIM);
    float4 w1  = *(const float4*)(gW + (size_t)ko*DIM + 4);
    float4 w2  = *(const float4*)(gW + (size_t)ko*DIM + 8);
    float4 w3  = *(const float4*)(gW + (size_t)ko*DIM + 12);
    int4 pa0, pa1;
    pa0.x = pk2(a00.x,a00.y); pa0.y = pk2(a00.z,a00.w);
    pa0.z = pk2(a01.x,a01.y); pa0.w = pk2(a01.z,a01.w);
    pa1.x = pk2(a10.x,a10.y); pa1.y = pk2(a10.z,a10.w);
    pa1.z = pk2(a11.x,a11.y); pa1.w = pk2(a11.z,a11.w);
    u16 wb[16];
    wb[0]=f2bf(w0.x); wb[1]=f2bf(w0.y); wb[2]=f2bf(w0.z); wb[3]=f2bf(w0.w);
    wb[4]=f2bf(w1.x); wb[5]=f2bf(w1.y); wb[6]=f2bf(w1.z); wb[7]=f2bf(w1.w);
    wb[8]=f2bf(w2.x); wb[9]=f2bf(w2.y); wb[10]=f2bf(w2.z); wb[11]=f2bf(w2.w);
    wb[12]=f2bf(w3.x); wb[13]=f2bf(w3.y); wb[14]=f2bf(w3.z); wb[15]=f2bf(w3.w);
    __syncthreads();
    *(int4*)(As + sr*40 + sc)      = pa0;
    *(int4*)(As + (64+sr)*40 + sc) = pa1;
    #pragma unroll
    for (int j=0;j<16;++j) Bs[(bc+j)*40 + br] = wb[j];
    __syncthreads();
    bf16x8 af[4], bfr[4];
    #pragma unroll
    for (int mt=0; mt<4; ++mt) af[mt]  = *(const bf16x8*)(As + (wm + mt*16 + l15)*40 + quad*8);
    #pragma unroll
    for (int nt=0; nt<4; ++nt) bfr[nt] = *(const bf16x8*)(Bs + (wn + nt*16 + l15)*40 + quad*8);
    #pragma unroll
    for (int mt=0; mt<4; ++mt)
      #pragma unroll
      for (int nt=0; nt<4; ++nt)
        acc[mt][nt] = __builtin_amdgcn_mfma_f32_16x16x32_bf16(af[mt], bfr[nt], acc[mt][nt], 0, 0, 0);
  }
  qkv_epilogue(z, m0, n0, wm, wn, quad, l15, acc, bias, qb, kf_out, vf_out);
}

// ---------------- flash attention: deferred-PV role split (unchanged from R11) ----------------
__global__ __launch_bounds__(256, 2) void attn(
    const u16* __restrict__ Qb, const u16* __restrict__ Kf,
    const u16* __restrict__ Vf, float* __restrict__ out)
{
  int fid = blockIdx.x;                 // 0..511
  int xcd  = fid & 7;                   // XCD assignment (id % 8)
  int hpar = (fid >> 3) & 1;
  int qb   = fid >> 4;                  // 0..31
  int h    = xcd*2 + hpar;              // heads {2x, 2x+1} pinned to XCD x

  int t = threadIdx.x, wave = t >> 6, lane = t & 63, quad = lane >> 4, l15 = lane & 15;
  int q0 = qb * 128 + wave * 32;
  int dg = (wave ^ (fid >> 8)) & 1;     // 0 = natural, 1 = deferred-PV

  __shared__ __align__(16) u16 Ks0[4096], Ks1[4096], Vs0[4096], Vs1[4096];

  const u16* Kfh = Kf + (size_t)h * 262144;
  const u16* Vfh = Vf + (size_t)h * 262144;

  bf16x8 qf[2][2];
  #pragma unroll
  for (int qs=0; qs<2; ++qs){
    const u16* Qp = Qb + (size_t)(q0 + qs*16 + l15)*DIM + h*HD;
    qf[qs][0] = *(const bf16x8*)(Qp + quad*8);
    qf[qs][1] = *(const bf16x8*)(Qp + 32 + quad*8);
  }

  f32x4 O[2][4];
  #pragma unroll
  for (int qs=0; qs<2; ++qs)
    #pragma unroll
    for (int dt=0; dt<4; ++dt) O[qs][dt] = (f32x4){0.f,0.f,0.f,0.f};
  float lsum[2] = {0.f, 0.f};

  typedef union { uint4 u; bf16x8 v; } pfu;

#define STAGE(KS, VS, T)                                                         \
  do {                                                                           \
    const u16* kg_ = Kfh + (size_t)(T)*4096 + t*8;                               \
    ld2lds16(kg_,        KS + t*8);                                              \
    ld2lds16(kg_ + 2048, KS + t*8 + 2048);                                       \
    const u16* vg_ = Vfh + (size_t)(T)*4096 + t*8;                               \
    ld2lds16(vg_,        VS + t*8);                                              \
    ld2lds16(vg_ + 2048, VS + t*8 + 2048);                                       \
  } while(0)

#define QK_EXP(KS, PF)                                                           \
  do {                                                                           \
    bf16x8 kfr[4][2];                                                            \
    _Pragma("unroll")                                                            \
    for (int kn=0; kn<4; ++kn)                                                   \
      _Pragma("unroll")                                                          \
      for (int hf=0; hf<2; ++hf)                                                 \
        kfr[kn][hf] = *(const bf16x8*)((KS) + (kn*2+hf)*512 + lane*8);           \
    f32x4 st[2][4];                                                              \
    __builtin_amdgcn_s_setprio(1);                                               \
    _Pragma("unroll")                                                            \
    for (int qs=0; qs<2; ++qs)                                                   \
      _Pragma("unroll")                                                          \
      for (int kn=0; kn<4; ++kn){                                                \
        f32x4 zz = (f32x4){0.f,0.f,0.f,0.f};                                     \
        zz = __builtin_amdgcn_mfma_f32_16x16x32_bf16(kfr[kn][0], qf[qs][0], zz, 0,0,0); \
        zz = __builtin_amdgcn_mfma_f32_16x16x32_bf16(kfr[kn][1], qf[qs][1], zz, 0,0,0); \
        st[qs][kn] = zz;                                                         \
      }                                                                          \
    __builtin_amdgcn_s_setprio(0);                                               \
    _Pragma("unroll")                                                            \
    for (int qs=0; qs<2; ++qs){                                                  \
      float ls = 0.f;                                                            \
      _Pragma("unroll")                                                          \
      for (int kn=0; kn<4; ++kn)                                                 \
        _Pragma("unroll")                                                        \
        for (int r=0; r<4; ++r){                                                 \
          float p = __builtin_amdgcn_exp2f(st[qs][kn][r]);                       \
          st[qs][kn][r] = p; ls += p;                                            \
        }                                                                        \
      lsum[qs] += ls;                                                            \
      PF[qs][0].u.x = pk2(st[qs][0][0], st[qs][0][1]);                           \
      PF[qs][0].u.y = pk2(st[qs][0][2], st[qs][0][3]);                           \
      PF[qs][0].u.z = pk2(st[qs][1][0], st[qs][1][1]);                           \
      PF[qs][0].u.w = pk2(st[qs][1][2], st[qs][1][3]);                           \
      PF[qs][1].u.x = pk2(st[qs][2][0], st[qs][2][1]);                           \
      PF[qs][1].u.y = pk2(st[qs][2][2], st[qs][2][3]);                           \
      PF[qs][1].u.z = pk2(st[qs][3][0], st[qs][3][1]);                           \
      PF[qs][1].u.w = pk2(st[qs][3][2], st[qs][3][3]);                           \
    }                                                                            \
  } while(0)

#define LOADV(VFR, VS)                                                           \
  do {                                                                           \
    _Pragma("unroll")                                                            \
    for (int dt=0; dt<4; ++dt)                                                   \
      _Pragma("unroll")                                                          \
      for (int c2=0; c2<2; ++c2)                                                 \
        VFR[dt][c2] = *(const bf16x8*)((VS) + (dt*2+c2)*512 + lane*8);           \
  } while(0)

#define PV(PF, VFR)                                                              \
  do {                                                                           \
    __builtin_amdgcn_s_setprio(1);                                               \
    _Pragma("unroll")                                                            \
    for (int qs=0; qs<2; ++qs)                                                   \
      _Pragma("unroll")                                                          \
      for (int dt=0; dt<4; ++dt){                                                \
        f32x4 o = O[qs][dt];                                                     \
        o = __builtin_amdgcn_mfma_f32_16x16x32_bf16(VFR[dt][0], PF[qs][0].v, o, 0,0,0); \
        o = __builtin_amdgcn_mfma_f32_16x16x32_bf16(VFR[dt][1], PF[qs][1].v, o, 0,0,0); \
        O[qs][dt] = o;                                                           \
      }                                                                          \
    __builtin_amdgcn_s_setprio(0);                                               \
  } while(0)

#define COMPUTE(KS, VS, FIRST)                                                   \
  do {                                                                           \
    if (!dg){                                                                    \
      pfu pfN[2][2]; bf16x8 vfrN[4][2];                                          \
      QK_EXP(KS, pfN);                                                           \
      LOADV(vfrN, VS);                                                           \
      PV(pfN, vfrN);                                                             \
    } else {                                                                     \
      if (!(FIRST)) PV(pfC, vfrC);                                               \
      QK_EXP(KS, pfC);                                                           \
      LOADV(vfrC, VS);                                                           \
    }                                                                            \
  } while(0)

  pfu pfC[2][2];
  bf16x8 vfrC[4][2];

  STAGE(Ks0, Vs0, 0);
  __syncthreads();
  STAGE(Ks1, Vs1, 1);
  COMPUTE(Ks0, Vs0, 1);
  __syncthreads();

  for (int kt = 1; kt < 63; kt += 2){
    STAGE(Ks0, Vs0, kt+1);
    COMPUTE(Ks1, Vs1, 0);
    __syncthreads();
    STAGE(Ks1, Vs1, kt+2);
    COMPUTE(Ks0, Vs0, 0);
    __syncthreads();
  }
  COMPUTE(Ks1, Vs1, 0);
  if (dg) PV(pfC, vfrC);

#undef STAGE
#undef QK_EXP
#undef LOADV
#undef PV
#undef COMPUTE

  #pragma unroll
  for (int qs=0; qs<2; ++qs){
    float l = lsum[qs];
    l += __shfl_xor(l, 16, 64);
    l += __shfl_xor(l, 32, 64);
    float inv = 1.0f / l;
    int query = q0 + qs*16 + l15;
    #pragma unroll
    for (int dt=0; dt<4; ++dt){
      float4 v;
      v.x = O[qs][dt][0]*inv; v.y = O[qs][dt][1]*inv;
      v.z = O[qs][dt][2]*inv; v.w = O[qs][dt][3]*inv;
      *(float4*)(out + (size_t)query*DIM + h*HD + dt*16 + quad*4) = v;
    }
  }
}

extern "C" void kernel_launch(void* const* d_in, const int* in_sizes, int n_in,
                              void* d_out, int out_size, void* d_ws, size_t ws_size,
                              hipStream_t stream)
{
  const float* X  = (const float*)d_in[0];
  const float* Wq = (const float*)d_in[1];
  const float* bq = (const float*)d_in[2];
  const float* Wk = (const float*)d_in[3];
  const float* bk = (const float*)d_in[4];
  const float* Wv = (const float*)d_in[5];
  const float* bv = (const float*)d_in[6];
  float* out = (float*)d_out;
  u16*   ws  = (u16*)d_ws;

  const size_t SD = (size_t)S_LEN * DIM;
  const size_t need_fast = (4*SD + 3*(size_t)DIM*DIM) * sizeof(u16);  // ~38 MB
  const size_t need_min  = (size_t)24 * 1024 * 1024;

  if (ws_size >= need_fast){
    u16* xbf = ws;
    u16* wt  = xbf + SD;
    u16* qb  = wt + 3*(size_t)DIM*DIM;
    u16* kf  = qb + SD;
    u16* vf  = kf + SD;
    conv_x       <<<dim3((int)(SD/8/256)), 256, 0, stream>>>(X, xbf);
    transpose_w  <<<dim3(16,16,3), 256, 0, stream>>>(Wq, Wk, Wv, wt);
    qkv_gemm_fast<<<dim3(768), 256, 0, stream>>>(xbf, wt, bq, bk, bv, qb, kf, vf);
    attn         <<<dim3(512), 256, 0, stream>>>(qb, kf, vf, out);
  } else if (ws_size >= need_min){
    u16* qb = ws;
    u16* kf = qb + SD;
    u16* vf = kf + SD;
    qkv_gemm_legacy<<<dim3(32, 8, 3), 256, 0, stream>>>(X, Wq, Wk, Wv, bq, bk, bv, qb, kf, vf);
    attn           <<<dim3(512), 256, 0, stream>>>(qb, kf, vf, out);
  } else {
    fill_sentinel<<<(out_size + 255)/256, 256, 0, stream>>>(out, out_size);
  }
}

// Round 13
// 205.248 us; speedup vs baseline: 1.0229x; 1.0176x over previous
//
#include <hip/hip_runtime.h>
#include <hip/hip_bf16.h>

#define S_LEN 4096
#define DIM   1024
#define NH    16
#define HD    64

typedef unsigned short u16;
typedef short  bf16x8 __attribute__((ext_vector_type(8)));
typedef float  f32x4  __attribute__((ext_vector_type(4)));

__device__ __forceinline__ u16 f2bf(float f){
  union { float f; unsigned u; } x; x.f = f;
  unsigned u = x.u;
  return (u16)((u + 0x7FFFu + ((u >> 16) & 1u)) >> 16);
}
__device__ __forceinline__ unsigned pk2(float a, float b){
  union { __hip_bfloat162 h; unsigned u; } x;
  x.h = __float22bfloat162_rn(float2{a, b});
  return x.u;
}
// async global->LDS, 16B per lane (dest must be wave-uniform base + lane*16)
__device__ __forceinline__ void ld2lds16(const u16* g, u16* l){
  __builtin_amdgcn_global_load_lds((const __attribute__((address_space(1))) void*)g,
                                   (__attribute__((address_space(3))) void*)l, 16, 0, 0);
}

// Q pre-scale: 1/sqrt(64) * log2(e)  (softmax in exp2 domain; v_exp_f32 = 2^x)
#define QSCALE 0.1803368801111204f

__global__ __launch_bounds__(256) void fill_sentinel(float* __restrict__ out, int n){
  int i = blockIdx.x * 256 + threadIdx.x;
  if (i < n) out[i] = 77.0f;
}

// ---------------- fused prep: X fp32->bf16 (blocks 0..2047) + W transpose (2048..2815) ----------------
__global__ __launch_bounds__(256) void prep_fused(
    const float* __restrict__ X, u16* __restrict__ Xb,
    const float* __restrict__ W0, const float* __restrict__ W1, const float* __restrict__ W2,
    u16* __restrict__ Wt)
{
  __shared__ __align__(16) u16 tile[64*72];
  int b = blockIdx.x;
  int t = threadIdx.x;
  if (b < 2048){
    size_t i = ((size_t)b * 256 + t) * 8;
    float4 v0 = *(const float4*)(X + i);
    float4 v1 = *(const float4*)(X + i + 4);
    uint4 w;
    w.x = pk2(v0.x, v0.y); w.y = pk2(v0.z, v0.w);
    w.z = pk2(v1.x, v1.y); w.w = pk2(v1.z, v1.w);
    *(uint4*)(Xb + i) = w;
    return;
  }
  int tid = b - 2048;                 // 0..767
  int z   = tid >> 8;
  int rem = tid & 255;
  int k0  = (rem & 15) * 64, n0 = (rem >> 4) * 64;
  const float* W = z==0 ? W0 : z==1 ? W1 : W2;
  u16* T = Wt + (size_t)z * DIM * DIM;
  #pragma unroll
  for (int i = 0; i < 4; ++i){
    int idx = t + i*256;
    int row = idx >> 4, col4 = (idx & 15) * 4;
    float4 v = *(const float4*)(W + (size_t)(k0+row)*DIM + n0 + col4);
    tile[(col4+0)*72 + row] = f2bf(v.x);
    tile[(col4+1)*72 + row] = f2bf(v.y);
    tile[(col4+2)*72 + row] = f2bf(v.z);
    tile[(col4+3)*72 + row] = f2bf(v.w);
  }
  __syncthreads();
  #pragma unroll
  for (int i = 0; i < 2; ++i){
    int idx = t + i*256;
    int n = idx >> 3, k16 = (idx & 7) * 8;
    *(int4*)(T + (size_t)(n0+n)*DIM + k0 + k16) = *(const int4*)(tile + n*72 + k16);
  }
}

// ---------------- shared epilogue: C-frags -> Q / Kf / Vf ----------------
// Vf key-slot mapping (R4): slot (c2, q_slot, jj) holds phys key
//   s = 16*(2*c2 + (jj>>2)) + 4*q_slot + (jj&3)
// chosen so that attn's PV B-operand is a pure register concat of the QK
// C-frags after exp (zero cross-lane traffic, no LDS P roundtrip).
__device__ __forceinline__ void qkv_epilogue(
    int z, int m0, int n0, int wm, int wn, int quad, int l15,
    const f32x4 acc[4][4], const float* bias,
    u16* __restrict__ qb, u16* __restrict__ kf_out, u16* __restrict__ vf_out)
{
  #pragma unroll
  for (int nt=0; nt<4; ++nt){
    int n = n0 + wn + nt*16 + l15;
    float bv = bias[n];
    int h = n >> 6, d = n & 63;
    #pragma unroll
    for (int mt=0; mt<4; ++mt){
      int mb = m0 + wm + mt*16 + quad*4;   // C/D: row=quad*4+reg, col=l15
      f32x4 c = acc[mt][nt];
      if (z == 0){
        #pragma unroll
        for (int r=0; r<4; ++r)
          qb[(size_t)(mb + r)*DIM + n] = f2bf((c[r] + bv) * QSCALE);
      } else if (z == 1){
        int half = d >> 5, quadk = (d >> 3) & 3, j = d & 7;
        #pragma unroll
        for (int r=0; r<4; ++r){
          int s = mb + r;
          size_t idx = ((((size_t)h*256 + (s >> 4))*2 + half)*64 + quadk*16 + (s & 15))*8 + j;
          kf_out[idx] = f2bf(c[r] + bv);
        }
      } else {
        // keys mb..mb+3: kn,q_slot,c2 constant across r; jj = jj0 + r
        int kt64 = mb >> 6;
        int kn   = (mb >> 4) & 3;
        int qsl  = (mb >> 2) & 3;
        int h2   = kn >> 1;
        int jj0  = (kn & 1) * 4;
        int dt = d >> 4, dl = d & 15;
        size_t base = (((((size_t)h*64 + kt64)*4 + dt)*2 + h2)*64 + qsl*16 + dl)*8 + jj0;
        ushort4 p;
        p.x = f2bf(c[0]+bv); p.y = f2bf(c[1]+bv);
        p.z = f2bf(c[2]+bv); p.w = f2bf(c[3]+bv);
        *(ushort4*)(vf_out + base) = p;
      }
    }
  }
}

// ---------------- fast QKV GEMM: BK=64, half the barriers ----------------
// R13: the 2-barrier BK=32 loop ran 64 full barrier drains over K=1024 and the
// GEMM measured ~90-100us (~270 TF). BK=64 halves the barrier count (32 total):
// As/Bs = 128x64 u16 (32 KB), 16 K-iterations, 32 MFMA each (two K-halves into
// the same acc in the SAME order -> bit-identical numerics).
// Rows are now 128 B = 32 banks, so un-swizzled frag reads would be a 32-way
// conflict; per rule #21 the gload_lds dest stays LINEAR and the GLOBAL source
// chunk is pre-permuted per-lane (chunk c' holds global chunk c'^(row&7));
// reads use chunk (kh*4+quad)^(l15&7). All offsets static per lane.
// XCD-locality grid map kept from R12.
__global__ __launch_bounds__(256) void qkv_gemm_fast(
    const u16* __restrict__ Xbf, const u16* __restrict__ Wt,
    const float* __restrict__ b0, const float* __restrict__ b1, const float* __restrict__ b2,
    u16* __restrict__ qb, u16* __restrict__ kf_out, u16* __restrict__ vf_out)
{
  int fid = blockIdx.x;                 // 0..767
  int z   = fid >> 8;                   // 0..2
  int r   = fid & 255;
  int m0  = (((r & 7) << 2) + ((r >> 3) & 3)) * 128;  // XCD r&7 owns m-tiles [xcd*4, xcd*4+4)
  int n0  = (r >> 5) * 128;                            // 0..7

  const u16* Wz = Wt + (size_t)z * DIM * DIM;
  const float* bias = z==0 ? b0 : z==1 ? b1 : b2;

  __shared__ __align__(16) u16 As[128*64];
  __shared__ __align__(16) u16 Bs[128*64];

  int t = threadIdx.x, wave = t >> 6, lane = t & 63, quad = lane >> 4, l15 = lane & 15;
  int wm = (wave >> 1) * 64, wn = (wave & 1) * 64;

  f32x4 acc[4][4];
  #pragma unroll
  for (int i=0;i<4;++i)
    #pragma unroll
    for (int j=0;j<4;++j) acc[i][j] = (f32x4){0.f,0.f,0.f,0.f};

  // staging: 4 gloads per matrix per kt; gload i covers rows [32i, 32i+32)
  int srow8  = t >> 3;                      // row within 32-row group (0..31)
  int schunk = t & 7;                       // linear LDS chunk (16B units)
  int gchunk = schunk ^ (srow8 & 7);        // pre-swizzled global chunk
  const u16* gA = Xbf + (size_t)(m0 + srow8)*DIM + gchunk*8;
  const u16* gB = Wz  + (size_t)(n0 + srow8)*DIM + gchunk*8;
  u16* lA = As + srow8*64 + schunk*8;
  u16* lB = Bs + srow8*64 + schunk*8;

  for (int kt = 0; kt < 16; ++kt){
    int ko = kt * 64;
    __syncthreads();
    #pragma unroll
    for (int i=0;i<4;++i){
      ld2lds16(gA + (size_t)(32*i)*DIM + ko, lA + 32*i*64);
      ld2lds16(gB + (size_t)(32*i)*DIM + ko, lB + 32*i*64);
    }
    __syncthreads();
    bf16x8 af[2][4], bfr[2][4];
    #pragma unroll
    for (int kh=0; kh<2; ++kh){
      #pragma unroll
      for (int mt=0; mt<4; ++mt){
        int row = wm + mt*16 + l15;
        int c = (kh*4 + quad) ^ (l15 & 7);
        af[kh][mt] = *(const bf16x8*)(As + row*64 + c*8);
      }
      #pragma unroll
      for (int nt=0; nt<4; ++nt){
        int row = wn + nt*16 + l15;
        int c = (kh*4 + quad) ^ (l15 & 7);
        bfr[kh][nt] = *(const bf16x8*)(Bs + row*64 + c*8);
      }
    }
    #pragma unroll
    for (int mt=0; mt<4; ++mt)
      #pragma unroll
      for (int nt=0; nt<4; ++nt){
        acc[mt][nt] = __builtin_amdgcn_mfma_f32_16x16x32_bf16(af[0][mt], bfr[0][nt], acc[mt][nt], 0, 0, 0);
        acc[mt][nt] = __builtin_amdgcn_mfma_f32_16x16x32_bf16(af[1][mt], bfr[1][nt], acc[mt][nt], 0, 0, 0);
      }
  }
  qkv_epilogue(z, m0, n0, wm, wn, quad, l15, acc, bias, qb, kf_out, vf_out);
}

// ---------------- legacy QKV GEMM (fp32 in; used when ws < 38 MB) ----------------
__global__ __launch_bounds__(256) void qkv_gemm_legacy(
    const float* __restrict__ X,
    const float* __restrict__ Wq, const float* __restrict__ Wk, const float* __restrict__ Wv,
    const float* __restrict__ b0, const float* __restrict__ b1, const float* __restrict__ b2,
    u16* __restrict__ qb, u16* __restrict__ kf_out, u16* __restrict__ vf_out)
{
  int z = blockIdx.z;
  const float* W    = z==0 ? Wq : z==1 ? Wk : Wv;
  const float* bias = z==0 ? b0 : z==1 ? b1 : b2;

  __shared__ __align__(16) u16 As[128*40];
  __shared__ __align__(16) u16 Bs[128*40];

  int m0 = blockIdx.x * 128, n0 = blockIdx.y * 128;
  int t = threadIdx.x, wave = t >> 6, lane = t & 63, quad = lane >> 4, l15 = lane & 15;
  int wm = (wave >> 1) * 64, wn = (wave & 1) * 64;

  f32x4 acc[4][4];
  #pragma unroll
  for (int i=0;i<4;++i)
    #pragma unroll
    for (int j=0;j<4;++j) acc[i][j] = (f32x4){0.f,0.f,0.f,0.f};

  int sr = t >> 2, sc = (t & 3) * 8;
  const float* gA0 = X + (size_t)(m0 + sr) * DIM + sc;
  const float* gA1 = X + (size_t)(m0 + 64 + sr) * DIM + sc;
  int br = t >> 3, bc = (t & 7) * 16;
  const float* gW = W + (size_t)br * DIM + n0 + bc;

  for (int kt = 0; kt < 32; ++kt){
    int ko = kt * 32;
    float4 a00 = *(const float4*)(gA0 + ko);
    float4 a01 = *(const float4*)(gA0 + ko + 4);
    float4 a10 = *(const float4*)(gA1 + ko);
    float4 a11 = *(const float4*)(gA1 + ko + 4);
    float4 w0  = *(const float4*)(gW + (size_t)ko*DIM);
    float4 w1  = *(const float4*)(gW + (size_t)ko*DIM + 4);
    float4 w2  = *(const float4*)(gW + (size_t)ko*DIM + 8);
    float4 w3  = *(const float4*)(gW + (size_t)ko*DIM + 12);
    int4 pa0, pa1;
    pa0.x = pk2(a00.x,a00.y); pa0.y = pk2(a00.z,a00.w);
    pa0.z = pk2(a01.x,a01.y); pa0.w = pk2(a01.z,a01.w);
    pa1.x = pk2(a10.x,a10.y); pa1.y = pk2(a10.z,a10.w);
    pa1.z = pk2(a11.x,a11.y); pa1.w = pk2(a11.z,a11.w);
    u16 wb[16];
    wb[0]=f2bf(w0.x); wb[1]=f2bf(w0.y); wb[2]=f2bf(w0.z); wb[3]=f2bf(w0.w);
    wb[4]=f2bf(w1.x); wb[5]=f2bf(w1.y); wb[6]=f2bf(w1.z); wb[7]=f2bf(w1.w);
    wb[8]=f2bf(w2.x); wb[9]=f2bf(w2.y); wb[10]=f2bf(w2.z); wb[11]=f2bf(w2.w);
    wb[12]=f2bf(w3.x); wb[13]=f2bf(w3.y); wb[14]=f2bf(w3.z); wb[15]=f2bf(w3.w);
    __syncthreads();
    *(int4*)(As + sr*40 + sc)      = pa0;
    *(int4*)(As + (64+sr)*40 + sc) = pa1;
    #pragma unroll
    for (int j=0;j<16;++j) Bs[(bc+j)*40 + br] = wb[j];
    __syncthreads();
    bf16x8 af[4], bfr[4];
    #pragma unroll
    for (int mt=0; mt<4; ++mt) af[mt]  = *(const bf16x8*)(As + (wm + mt*16 + l15)*40 + quad*8);
    #pragma unroll
    for (int nt=0; nt<4; ++nt) bfr[nt] = *(const bf16x8*)(Bs + (wn + nt*16 + l15)*40 + quad*8);
    #pragma unroll
    for (int mt=0; mt<4; ++mt)
      #pragma unroll
      for (int nt=0; nt<4; ++nt)
        acc[mt][nt] = __builtin_amdgcn_mfma_f32_16x16x32_bf16(af[mt], bfr[nt], acc[mt][nt], 0, 0, 0);
  }
  qkv_epilogue(z, m0, n0, wm, wn, quad, l15, acc, bias, qb, kf_out, vf_out);
}

// ---------------- flash attention: deferred-PV role split (unchanged from R11) ----------------
__global__ __launch_bounds__(256, 2) void attn(
    const u16* __restrict__ Qb, const u16* __restrict__ Kf,
    const u16* __restrict__ Vf, float* __restrict__ out)
{
  int fid = blockIdx.x;                 // 0..511
  int xcd  = fid & 7;                   // XCD assignment (id % 8)
  int hpar = (fid >> 3) & 1;
  int qb   = fid >> 4;                  // 0..31
  int h    = xcd*2 + hpar;              // heads {2x, 2x+1} pinned to XCD x

  int t = threadIdx.x, wave = t >> 6, lane = t & 63, quad = lane >> 4, l15 = lane & 15;
  int q0 = qb * 128 + wave * 32;
  int dg = (wave ^ (fid >> 8)) & 1;     // 0 = natural, 1 = deferred-PV

  __shared__ __align__(16) u16 Ks0[4096], Ks1[4096], Vs0[4096], Vs1[4096];

  const u16* Kfh = Kf + (size_t)h * 262144;
  const u16* Vfh = Vf + (size_t)h * 262144;

  bf16x8 qf[2][2];
  #pragma unroll
  for (int qs=0; qs<2; ++qs){
    const u16* Qp = Qb + (size_t)(q0 + qs*16 + l15)*DIM + h*HD;
    qf[qs][0] = *(const bf16x8*)(Qp + quad*8);
    qf[qs][1] = *(const bf16x8*)(Qp + 32 + quad*8);
  }

  f32x4 O[2][4];
  #pragma unroll
  for (int qs=0; qs<2; ++qs)
    #pragma unroll
    for (int dt=0; dt<4; ++dt) O[qs][dt] = (f32x4){0.f,0.f,0.f,0.f};
  float lsum[2] = {0.f, 0.f};

  typedef union { uint4 u; bf16x8 v; } pfu;

#define STAGE(KS, VS, T)                                                         \
  do {                                                                           \
    const u16* kg_ = Kfh + (size_t)(T)*4096 + t*8;                               \
    ld2lds16(kg_,        KS + t*8);                                              \
    ld2lds16(kg_ + 2048, KS + t*8 + 2048);                                       \
    const u16* vg_ = Vfh + (size_t)(T)*4096 + t*8;                               \
    ld2lds16(vg_,        VS + t*8);                                              \
    ld2lds16(vg_ + 2048, VS + t*8 + 2048);                                       \
  } while(0)

#define QK_EXP(KS, PF)                                                           \
  do {                                                                           \
    bf16x8 kfr[4][2];                                                            \
    _Pragma("unroll")                                                            \
    for (int kn=0; kn<4; ++kn)                                                   \
      _Pragma("unroll")                                                          \
      for (int hf=0; hf<2; ++hf)                                                 \
        kfr[kn][hf] = *(const bf16x8*)((KS) + (kn*2+hf)*512 + lane*8);           \
    f32x4 st[2][4];                                                              \
    __builtin_amdgcn_s_setprio(1);                                               \
    _Pragma("unroll")                                                            \
    for (int qs=0; qs<2; ++qs)                                                   \
      _Pragma("unroll")                                                          \
      for (int kn=0; kn<4; ++kn){                                                \
        f32x4 zz = (f32x4){0.f,0.f,0.f,0.f};                                     \
        zz = __builtin_amdgcn_mfma_f32_16x16x32_bf16(kfr[kn][0], qf[qs][0], zz, 0,0,0); \
        zz = __builtin_amdgcn_mfma_f32_16x16x32_bf16(kfr[kn][1], qf[qs][1], zz, 0,0,0); \
        st[qs][kn] = zz;                                                         \
      }                                                                          \
    __builtin_amdgcn_s_setprio(0);                                               \
    _Pragma("unroll")                                                            \
    for (int qs=0; qs<2; ++qs){                                                  \
      float ls = 0.f;                                                            \
      _Pragma("unroll")                                                          \
      for (int kn=0; kn<4; ++kn)                                                 \
        _Pragma("unroll")                                                        \
        for (int r=0; r<4; ++r){                                                 \
          float p = __builtin_amdgcn_exp2f(st[qs][kn][r]);                       \
          st[qs][kn][r] = p; ls += p;                                            \
        }                                                                        \
      lsum[qs] += ls;                                                            \
      PF[qs][0].u.x = pk2(st[qs][0][0], st[qs][0][1]);                           \
      PF[qs][0].u.y = pk2(st[qs][0][2], st[qs][0][3]);                           \
      PF[qs][0].u.z = pk2(st[qs][1][0], st[qs][1][1]);                           \
      PF[qs][0].u.w = pk2(st[qs][1][2], st[qs][1][3]);                           \
      PF[qs][1].u.x = pk2(st[qs][2][0], st[qs][2][1]);                           \
      PF[qs][1].u.y = pk2(st[qs][2][2], st[qs][2][3]);                           \
      PF[qs][1].u.z = pk2(st[qs][3][0], st[qs][3][1]);                           \
      PF[qs][1].u.w = pk2(st[qs][3][2], st[qs][3][3]);                           \
    }                                                                            \
  } while(0)

#define LOADV(VFR, VS)                                                           \
  do {                                                                           \
    _Pragma("unroll")                                                            \
    for (int dt=0; dt<4; ++dt)                                                   \
      _Pragma("unroll")                                                          \
      for (int c2=0; c2<2; ++c2)                                                 \
        VFR[dt][c2] = *(const bf16x8*)((VS) + (dt*2+c2)*512 + lane*8);           \
  } while(0)

#define PV(PF, VFR)                                                              \
  do {                                                                           \
    __builtin_amdgcn_s_setprio(1);                                               \
    _Pragma("unroll")                                                            \
    for (int qs=0; qs<2; ++qs)                                                   \
      _Pragma("unroll")                                                          \
      for (int dt=0; dt<4; ++dt){                                                \
        f32x4 o = O[qs][dt];                                                     \
        o = __builtin_amdgcn_mfma_f32_16x16x32_bf16(VFR[dt][0], PF[qs][0].v, o, 0,0,0); \
        o = __builtin_amdgcn_mfma_f32_16x16x32_bf16(VFR[dt][1], PF[qs][1].v, o, 0,0,0); \
        O[qs][dt] = o;                                                           \
      }                                                                          \
    __builtin_amdgcn_s_setprio(0);                                               \
  } while(0)

#define COMPUTE(KS, VS, FIRST)                                                   \
  do {                                                                           \
    if (!dg){                                                                    \
      pfu pfN[2][2]; bf16x8 vfrN[4][2];                                          \
      QK_EXP(KS, pfN);                                                           \
      LOADV(vfrN, VS);                                                           \
      PV(pfN, vfrN);                                                             \
    } else {                                                                     \
      if (!(FIRST)) PV(pfC, vfrC);                                               \
      QK_EXP(KS, pfC);                                                           \
      LOADV(vfrC, VS);                                                           \
    }                                                                            \
  } while(0)

  pfu pfC[2][2];
  bf16x8 vfrC[4][2];

  STAGE(Ks0, Vs0, 0);
  __syncthreads();
  STAGE(Ks1, Vs1, 1);
  COMPUTE(Ks0, Vs0, 1);
  __syncthreads();

  for (int kt = 1; kt < 63; kt += 2){
    STAGE(Ks0, Vs0, kt+1);
    COMPUTE(Ks1, Vs1, 0);
    __syncthreads();
    STAGE(Ks1, Vs1, kt+2);
    COMPUTE(Ks0, Vs0, 0);
    __syncthreads();
  }
  COMPUTE(Ks1, Vs1, 0);
  if (dg) PV(pfC, vfrC);

#undef STAGE
#undef QK_EXP
#undef LOADV
#undef PV
#undef COMPUTE

  #pragma unroll
  for (int qs=0; qs<2; ++qs){
    float l = lsum[qs];
    l += __shfl_xor(l, 16, 64);
    l += __shfl_xor(l, 32, 64);
    float inv = 1.0f / l;
    int query = q0 + qs*16 + l15;
    #pragma unroll
    for (int dt=0; dt<4; ++dt){
      float4 v;
      v.x = O[qs][dt][0]*inv; v.y = O[qs][dt][1]*inv;
      v.z = O[qs][dt][2]*inv; v.w = O[qs][dt][3]*inv;
      *(float4*)(out + (size_t)query*DIM + h*HD + dt*16 + quad*4) = v;
    }
  }
}

extern "C" void kernel_launch(void* const* d_in, const int* in_sizes, int n_in,
                              void* d_out, int out_size, void* d_ws, size_t ws_size,
                              hipStream_t stream)
{
  const float* X  = (const float*)d_in[0];
  const float* Wq = (const float*)d_in[1];
  const float* bq = (const float*)d_in[2];
  const float* Wk = (const float*)d_in[3];
  const float* bk = (const float*)d_in[4];
  const float* Wv = (const float*)d_in[5];
  const float* bv = (const float*)d_in[6];
  float* out = (float*)d_out;
  u16*   ws  = (u16*)d_ws;

  const size_t SD = (size_t)S_LEN * DIM;
  const size_t need_fast = (4*SD + 3*(size_t)DIM*DIM) * sizeof(u16);  // ~38 MB
  const size_t need_min  = (size_t)24 * 1024 * 1024;

  if (ws_size >= need_fast){
    u16* xbf = ws;
    u16* wt  = xbf + SD;
    u16* qb  = wt + 3*(size_t)DIM*DIM;
    u16* kf  = qb + SD;
    u16* vf  = kf + SD;
    prep_fused   <<<dim3(2048 + 768), 256, 0, stream>>>(X, xbf, Wq, Wk, Wv, wt);
    qkv_gemm_fast<<<dim3(768), 256, 0, stream>>>(xbf, wt, bq, bk, bv, qb, kf, vf);
    attn         <<<dim3(512), 256, 0, stream>>>(qb, kf, vf, out);
  } else if (ws_size >= need_min){
    u16* qb = ws;
    u16* kf = qb + SD;
    u16* vf = kf + SD;
    qkv_gemm_legacy<<<dim3(32, 8, 3), 256, 0, stream>>>(X, Wq, Wk, Wv, bq, bk, bv, qb, kf, vf);
    attn           <<<dim3(512), 256, 0, stream>>>(qb, kf, vf, out);
  } else {
    fill_sentinel<<<(out_size + 255)/256, 256, 0, stream>>>(out, out_size);
  }
}